// Round 5
// baseline (181.633 us; speedup 1.0000x reference)
//
#include <hip/hip_runtime.h>

#define NB 32
#define NC 64
#define HW 25600          // 160*160
#define HW4 6400          // HW/4 (float4 per image)
#define BLKS_PER_B 25     // HW4 / 256
#define NBLOCKS 800       // NB * BLKS_PER_B
#define BN_EPS 1e-5f
#define LEAKY 0.1f

typedef float vfloat4 __attribute__((ext_vector_type(4)));  // native vec for nontemporal

// One fused kernel with a hand-rolled device-wide barrier:
//   phase 1: channel dot product, accumulator stays in registers;
//            per-block (sum,sumsq) -> partials; arrive on atomic counter.
//   spin barrier (thread 0 per block, s_sleep backoff).
//   phase 2: every block redundantly reduces the 800 partials in fixed order
//            (bitwise identical across blocks -> deterministic), applies
//            BN + LeakyReLU to the register accumulator, nontemporal store.
// __launch_bounds__(256,4): VGPR capped at 128 -> >=4 blocks/CU co-resident
// (1024 slots >= 800 blocks) -> spin barrier cannot deadlock.
__global__ __launch_bounds__(256, 4) void maskgen_onepass(
    const float* __restrict__ feats, const float* __restrict__ sf,
    const float* __restrict__ bn_w, const float* __restrict__ bn_b,
    float* __restrict__ out, float* __restrict__ partials,
    unsigned int* __restrict__ counter) {
    const int b = blockIdx.x / BLKS_PER_B;
    const int t = (blockIdx.x % BLKS_PER_B) * 256 + threadIdx.x;  // float4 idx in image

    __shared__ float s_sf[NC];
    __shared__ float s_red[8];
    __shared__ double s_dred[8];

    if (threadIdx.x < NC) s_sf[threadIdx.x] = sf[b * NC + threadIdx.x];
    __syncthreads();

    // ---- phase 1: dot product, accumulator in registers ----
    const float4* f4 = reinterpret_cast<const float4*>(feats) + (size_t)b * NC * HW4 + t;
    float4 acc = make_float4(0.f, 0.f, 0.f, 0.f);
#pragma unroll 16
    for (int c = 0; c < NC; ++c) {
        float4 v = f4[(size_t)c * HW4];
        float s = s_sf[c];
        acc.x = fmaf(v.x, s, acc.x);
        acc.y = fmaf(v.y, s, acc.y);
        acc.z = fmaf(v.z, s, acc.z);
        acc.w = fmaf(v.w, s, acc.w);
    }

    float lsum = (acc.x + acc.y) + (acc.z + acc.w);
    float lsq  = acc.x * acc.x + acc.y * acc.y + acc.z * acc.z + acc.w * acc.w;
#pragma unroll
    for (int off = 32; off > 0; off >>= 1) {
        lsum += __shfl_down(lsum, off, 64);
        lsq  += __shfl_down(lsq,  off, 64);
    }
    const int wave = threadIdx.x >> 6;
    if ((threadIdx.x & 63) == 0) { s_red[wave] = lsum; s_red[4 + wave] = lsq; }
    __syncthreads();

    if (threadIdx.x == 0) {
        partials[blockIdx.x]           = (s_red[0] + s_red[1]) + (s_red[2] + s_red[3]);
        partials[NBLOCKS + blockIdx.x] = (s_red[4] + s_red[5]) + (s_red[6] + s_red[7]);
        __threadfence();  // device-scope: partials visible across XCDs
        __hip_atomic_fetch_add(counter, 1u, __ATOMIC_ACQ_REL, __HIP_MEMORY_SCOPE_AGENT);
    }

    // ---- device-wide arrive/spin barrier ----
    if (threadIdx.x == 0) {
        while (__hip_atomic_load(counter, __ATOMIC_ACQUIRE, __HIP_MEMORY_SCOPE_AGENT)
               < (unsigned)NBLOCKS) {
            __builtin_amdgcn_s_sleep(8);
        }
    }
    __syncthreads();

    // ---- phase 2: redundant fixed-order stats (identical in every block) ----
    double s = 0.0, q = 0.0;
    for (int i = threadIdx.x; i < NBLOCKS; i += 256) {
        s += (double)__hip_atomic_load(&partials[i], __ATOMIC_RELAXED,
                                       __HIP_MEMORY_SCOPE_AGENT);
        q += (double)__hip_atomic_load(&partials[NBLOCKS + i], __ATOMIC_RELAXED,
                                       __HIP_MEMORY_SCOPE_AGENT);
    }
#pragma unroll
    for (int off = 32; off > 0; off >>= 1) {
        s += __shfl_down(s, off, 64);
        q += __shfl_down(q, off, 64);
    }
    if ((threadIdx.x & 63) == 0) { s_dred[wave] = s; s_dred[4 + wave] = q; }
    __syncthreads();

    const double S = (s_dred[0] + s_dred[1]) + (s_dred[2] + s_dred[3]);
    const double Q = (s_dred[4] + s_dred[5]) + (s_dred[6] + s_dred[7]);
    const double N = (double)NB * (double)HW;
    const double mean = S / N;
    const double var  = Q / N - mean * mean;
    const float inv   = rsqrtf((float)var + BN_EPS);
    const float scale = inv * bn_w[0];
    const float shift = bn_b[0] - (float)mean * scale;

    vfloat4 r;
    r.x = fmaf(acc.x, scale, shift); r.x = (r.x >= 0.f) ? r.x : LEAKY * r.x;
    r.y = fmaf(acc.y, scale, shift); r.y = (r.y >= 0.f) ? r.y : LEAKY * r.y;
    r.z = fmaf(acc.z, scale, shift); r.z = (r.z >= 0.f) ? r.z : LEAKY * r.z;
    r.w = fmaf(acc.w, scale, shift); r.w = (r.w >= 0.f) ? r.w : LEAKY * r.w;
    // nontemporal: don't evict L3-resident feats with the output write
    __builtin_nontemporal_store(r, reinterpret_cast<vfloat4*>(out) + (size_t)b * HW4 + t);
}

extern "C" void kernel_launch(void* const* d_in, const int* in_sizes, int n_in,
                              void* d_out, int out_size, void* d_ws, size_t ws_size,
                              hipStream_t stream) {
    const float* sf    = (const float*)d_in[0];   // [32,64,1,1]
    const float* feats = (const float*)d_in[1];   // [32,64,160,160]
    const float* bn_w  = (const float*)d_in[2];   // [1]
    const float* bn_b  = (const float*)d_in[3];   // [1]
    float* out      = (float*)d_out;              // [32,1,160,160] fp32
    float* partials = (float*)d_ws;               // 2*800 floats
    unsigned int* counter = (unsigned int*)(partials + 2 * NBLOCKS);

    // zero the barrier counter every call (deterministic, capture-legal)
    (void)hipMemsetAsync(counter, 0, sizeof(unsigned int), stream);

    maskgen_onepass<<<NBLOCKS, 256, 0, stream>>>(feats, sf, bn_w, bn_b,
                                                 out, partials, counter);
}

// Round 6
// 41.536 us; speedup vs baseline: 4.3729x; 4.3729x over previous
//
#include <hip/hip_runtime.h>

#define NB 32
#define NC 64
#define HW 25600          // 160*160
#define HW4 6400          // HW/4 (float4 per image)
#define BLKS_PER_B 25     // HW4 / 256
#define NBLOCKS 800       // NB * BLKS_PER_B
#define BN_EPS 1e-5f
#define LEAKY 0.1f

typedef float vfloat4 __attribute__((ext_vector_type(4)));  // native vec for nontemporal

// Pass 1: mask = einsum('bchw,bc->bhw') -> d_out (nontemporal store: don't
// evict the feats stream from L2); per-block (sum, sumsq) partials.
__global__ __launch_bounds__(256) void maskgen_pass1(
    const float* __restrict__ feats, const float* __restrict__ sf,
    float* __restrict__ mask, float* __restrict__ partials) {
    const int b = blockIdx.x / BLKS_PER_B;
    const int t = (blockIdx.x % BLKS_PER_B) * 256 + threadIdx.x;  // float4 idx within image

    __shared__ float s_sf[NC];
    if (threadIdx.x < NC) s_sf[threadIdx.x] = sf[b * NC + threadIdx.x];
    __syncthreads();

    const vfloat4* f4 = reinterpret_cast<const vfloat4*>(feats) + (size_t)b * NC * HW4 + t;
    // dual accumulators: more scheduling freedom for the load stream
    vfloat4 acc0 = {0.f, 0.f, 0.f, 0.f};
    vfloat4 acc1 = {0.f, 0.f, 0.f, 0.f};
#pragma unroll 8
    for (int c = 0; c < NC; c += 2) {
        vfloat4 v0 = f4[(size_t)c * HW4];
        vfloat4 v1 = f4[(size_t)(c + 1) * HW4];
        float s0 = s_sf[c], s1 = s_sf[c + 1];
        acc0.x = fmaf(v0.x, s0, acc0.x); acc1.x = fmaf(v1.x, s1, acc1.x);
        acc0.y = fmaf(v0.y, s0, acc0.y); acc1.y = fmaf(v1.y, s1, acc1.y);
        acc0.z = fmaf(v0.z, s0, acc0.z); acc1.z = fmaf(v1.z, s1, acc1.z);
        acc0.w = fmaf(v0.w, s0, acc0.w); acc1.w = fmaf(v1.w, s1, acc1.w);
    }
    vfloat4 acc = acc0 + acc1;
    __builtin_nontemporal_store(acc, reinterpret_cast<vfloat4*>(mask) + (size_t)b * HW4 + t);

    float lsum = (acc.x + acc.y) + (acc.z + acc.w);
    float lsq  = acc.x * acc.x + acc.y * acc.y + acc.z * acc.z + acc.w * acc.w;
#pragma unroll
    for (int off = 32; off > 0; off >>= 1) {
        lsum += __shfl_down(lsum, off, 64);
        lsq  += __shfl_down(lsq,  off, 64);
    }
    __shared__ float s_red[8];
    const int wave = threadIdx.x >> 6;
    if ((threadIdx.x & 63) == 0) { s_red[wave] = lsum; s_red[4 + wave] = lsq; }
    __syncthreads();
    if (threadIdx.x == 0) {
        partials[blockIdx.x]           = (s_red[0] + s_red[1]) + (s_red[2] + s_red[3]);
        partials[NBLOCKS + blockIdx.x] = (s_red[4] + s_red[5]) + (s_red[6] + s_red[7]);
    }
}

// Pass 2 (fused stats + apply): every block redundantly reduces the 800
// partials (fixed order -> identical result in all blocks, deterministic),
// then applies BN + LeakyReLU in-place. Mask data is dead after the read and
// out is never reread -> nontemporal both ways (preserve feats' L2/L3).
__global__ __launch_bounds__(256) void maskgen_pass2(
    float* __restrict__ mask, const float* __restrict__ partials,
    const float* __restrict__ bn_w, const float* __restrict__ bn_b) {
    double s = 0.0, q = 0.0;
    for (int i = threadIdx.x; i < NBLOCKS; i += 256) {
        s += (double)partials[i];
        q += (double)partials[NBLOCKS + i];
    }
#pragma unroll
    for (int off = 32; off > 0; off >>= 1) {
        s += __shfl_down(s, off, 64);
        q += __shfl_down(q, off, 64);
    }
    __shared__ double sh[8];
    const int wave = threadIdx.x >> 6;
    if ((threadIdx.x & 63) == 0) { sh[wave] = s; sh[4 + wave] = q; }
    __syncthreads();

    const double S = (sh[0] + sh[1]) + (sh[2] + sh[3]);
    const double Q = (sh[4] + sh[5]) + (sh[6] + sh[7]);
    const double N = (double)NB * (double)HW;
    const double mean = S / N;
    const double var  = Q / N - mean * mean;
    const float inv   = rsqrtf((float)var + BN_EPS);
    const float scale = inv * bn_w[0];
    const float shift = bn_b[0] - (float)mean * scale;

    const int i = blockIdx.x * 256 + threadIdx.x;  // float4 idx, grid = NB*HW4/256
    vfloat4 v = __builtin_nontemporal_load(reinterpret_cast<vfloat4*>(mask) + i);
    vfloat4 r;
    r.x = fmaf(v.x, scale, shift); r.x = (r.x >= 0.f) ? r.x : LEAKY * r.x;
    r.y = fmaf(v.y, scale, shift); r.y = (r.y >= 0.f) ? r.y : LEAKY * r.y;
    r.z = fmaf(v.z, scale, shift); r.z = (r.z >= 0.f) ? r.z : LEAKY * r.z;
    r.w = fmaf(v.w, scale, shift); r.w = (r.w >= 0.f) ? r.w : LEAKY * r.w;
    __builtin_nontemporal_store(r, reinterpret_cast<vfloat4*>(mask) + i);
}

extern "C" void kernel_launch(void* const* d_in, const int* in_sizes, int n_in,
                              void* d_out, int out_size, void* d_ws, size_t ws_size,
                              hipStream_t stream) {
    const float* sf    = (const float*)d_in[0];   // [32,64,1,1]
    const float* feats = (const float*)d_in[1];   // [32,64,160,160]
    const float* bn_w  = (const float*)d_in[2];   // [1]
    const float* bn_b  = (const float*)d_in[3];   // [1]
    float* out      = (float*)d_out;              // [32,1,160,160] fp32
    float* partials = (float*)d_ws;               // 2*800 floats

    maskgen_pass1<<<NBLOCKS, 256, 0, stream>>>(feats, sf, out, partials);
    maskgen_pass2<<<NBLOCKS, 256, 0, stream>>>(out, partials, bn_w, bn_b);
}